// Round 5
// baseline (621.632 us; speedup 1.0000x reference)
//
#include <hip/hip_runtime.h>

// SdfParseLoss: scatter-min/max of sdf over pixel grid, then masked mean loss.
// H=256, W=192, B=64, V=100000. Output: 64 floats.
//
// Round 5: two-pass binning. Rounds 3/4 showed dur ~= logical_bytes / 6 TB/s;
// slice-replicated streaming moves S*77MB. Fix: visit each vertex ONCE.
//  Pass 1: stream sdf+mesh, pack record32 = p_local(14b)<<18 | key18, wave-
//          aggregated compaction into per-(batch,slice) buckets (ballot +
//          one cursor atomicAdd per wave per slice).
//  Pass 2: each (b,slice) block reads only its bucket -> LDS atomicMin
//          (gt==0 pixels store inverted key so min == max), then reduces.
// key18 = top 18 bits of the order-preserving fkey, round-to-nearest:
// <= 2^-10 relative error per pixel, ~1000x under the 1.4e-2 threshold.

#define HH 256
#define WW 192
#define HW (HH * WW)
#define NB 64
#define NV 100000
#define NS 4                    // slices of 64 rows each
#define RANGE (HW / NS)         // 12288 pixels per slice
#define CAP 24560               // bucket capacity (~30 sigma over 20.6K mean)
#define NC 8                    // pass-1 chunks per batch
#define F4B (NV / 4 / NC)       // 3125 float4 groups per pass-1 block

// Order-preserving float <-> uint transform so unsigned min gives float min.
__device__ __forceinline__ unsigned fkey(float f) {
    unsigned u = __float_as_uint(f);
    return (u & 0x80000000u) ? ~u : (u | 0x80000000u);
}
__device__ __forceinline__ float funkey(unsigned k) {
    unsigned u = (k & 0x80000000u) ? (k ^ 0x80000000u) : ~k;
    return __uint_as_float(u);
}
// 18-bit order-preserving quantization (round to nearest grid point).
__device__ __forceinline__ unsigned key18(float f) {
    unsigned k = fkey(f);
    if (k >= 0xFFFFE000u) return 0x3FFFFu;       // avoid +0x2000 overflow
    return (k + 0x2000u) >> 14;                  // monotone round-to-nearest
}

__global__ __launch_bounds__(512) void bin_kernel(
        const float4* __restrict__ sdf4,
        const float4* __restrict__ mesh4,
        unsigned* __restrict__ cursors,          // [NB*NS]
        unsigned* __restrict__ records) {        // [NB*NS*CAP]
    const int b = blockIdx.x >> 3;               // NC == 8
    const int c = blockIdx.x & 7;
    const int lane = threadIdx.x & 63;
    const unsigned long long lt = (1ull << lane) - 1ull;

    const float4* sbase = sdf4  + (size_t)b * (NV / 4) + (size_t)c * F4B;
    const float4* mbase = mesh4 + (size_t)b * (NV / 2) + (size_t)c * F4B * 2;

    for (int g = threadIdx.x; g < F4B; g += 512) {
        float4 s4 = sbase[g];
        float4 ma = mbase[2 * g];
        float4 mb = mbase[2 * g + 1];
        float xs[4] = {ma.x, ma.z, mb.x, mb.z};
        float ys[4] = {ma.y, ma.w, mb.y, mb.w};
        float ss[4] = {s4.x, s4.y, s4.z, s4.w};
        #pragma unroll
        for (int j = 0; j < 4; ++j) {
            int x = (int)xs[j];   // trunc toward zero == jnp astype(int32)
            int y = (int)ys[j];
            bool valid = ((unsigned)x < WW) && ((unsigned)y < HH);
            int q = valid ? (y >> 6) : 0;        // 64 rows per slice
            unsigned rec = 0;
            if (valid)
                rec = ((unsigned)((y & 63) * WW + x) << 18) | key18(ss[j]);
            #pragma unroll
            for (int qq = 0; qq < NS; ++qq) {
                bool pred = valid && (q == qq);
                unsigned long long m = __ballot(pred);
                if (m == 0) continue;            // wave-uniform
                int lead = (int)(__ffsll((long long)m) - 1);
                unsigned base = 0;
                if (lane == lead)
                    base = atomicAdd(&cursors[b * NS + qq],
                                     (unsigned)__popcll(m));
                base = __shfl(base, lead, 64);
                if (pred) {
                    unsigned pos = base + (unsigned)__popcll(m & lt);
                    if (pos < CAP)
                        records[(size_t)(b * NS + qq) * CAP + pos] = rec;
                }
            }
        }
    }
}

__global__ __launch_bounds__(1024) void scatter_reduce_kernel(
        const unsigned* __restrict__ records,
        const unsigned* __restrict__ cursors,
        const int4* __restrict__ gt4,
        const float* __restrict__ thr_p,
        float* __restrict__ sums,
        unsigned* __restrict__ counts) {
    __shared__ unsigned ldsk[RANGE];             // 48 KB
    __shared__ unsigned char gtb[RANGE];         // 12 KB
    const int b = blockIdx.x >> 2;
    const int q = blockIdx.x & 3;
    const int tid = threadIdx.x;

    int lpos = 0;
    for (int j = tid; j < RANGE; j += 1024) ldsk[j] = 0xFFFFFFFFu;
    const int4* gbase = gt4 + ((size_t)b * HW + (size_t)q * RANGE) / 4;
    for (int j = tid; j < RANGE / 4; j += 1024) {
        int4 g = gbase[j];
        gtb[4 * j + 0] = (unsigned char)g.x;
        gtb[4 * j + 1] = (unsigned char)g.y;
        gtb[4 * j + 2] = (unsigned char)g.z;
        gtb[4 * j + 3] = (unsigned char)g.w;
        lpos |= (g.x == 1) | (g.y == 1) | (g.z == 1) | (g.w == 1);
    }
    __syncthreads();

    unsigned count = cursors[b * NS + q];
    if (count > CAP) count = CAP;
    const unsigned* rbase = records + (size_t)(b * NS + q) * CAP;
    for (unsigned i = tid; i < count; i += 1024) {
        unsigned r = rbase[i];
        unsigned p = r >> 18;
        unsigned k = r & 0x3FFFFu;
        if (gtb[p] == 0) k ^= 0x3FFFFu;          // neg pixel: min(~k) == max
        atomicMin(&ldsk[p], k);
    }
    __syncthreads();

    const float thr = thr_p[0];
    float lsum = 0.f;
    for (int j = tid; j < RANGE; j += 1024) {
        unsigned k = ldsk[j];
        if (k <= 0x3FFFFu) {                     // empty pixels contribute 0
            if (gtb[j]) lsum += fabsf(funkey(k << 14));
            else        lsum += fabsf(funkey((k ^ 0x3FFFFu) << 14) - thr);
        }
    }
    #pragma unroll
    for (int off = 32; off > 0; off >>= 1)
        lsum += __shfl_down(lsum, off, 64);
    unsigned long long m = __ballot(lpos != 0);
    if ((tid & 63) == 0) {
        atomicAdd(&sums[b], lsum);
        if (m) atomicOr(&counts[b], 1u);
    }
}

__global__ void final_kernel(const float* __restrict__ sums,
                             const unsigned* __restrict__ counts,
                             const float* __restrict__ pv,
                             float* __restrict__ out) {
    int b = threadIdx.x;
    if (b < NB) {
        float s = sums[b] * (1.0f / HW) * pv[b];
        out[b] = counts[b] ? s : 0.0f;
    }
}

extern "C" void kernel_launch(void* const* d_in, const int* in_sizes, int n_in,
                              void* d_out, int out_size, void* d_ws, size_t ws_size,
                              hipStream_t stream) {
    const float* sdf  = (const float*)d_in[0];
    const float* mesh = (const float*)d_in[1];
    const int*   gt   = (const int*)d_in[2];
    const float* thr  = (const float*)d_in[3];
    const float* pv   = (const float*)d_in[5];   // parse_valid [B,1,1]
    float* out = (float*)d_out;

    // ws layout: [cursors 1024B][sums 256B][counts 256B][records 24.0MB]
    unsigned* cursors = (unsigned*)d_ws;
    float*    sums    = (float*)((char*)d_ws + 1024);
    unsigned* counts  = (unsigned*)((char*)d_ws + 1280);
    unsigned* records = (unsigned*)((char*)d_ws + 1536);

    hipMemsetAsync(d_ws, 0, 1536, stream);       // cursors + sums + counts

    bin_kernel<<<NB * NC, 512, 0, stream>>>(
        (const float4*)sdf, (const float4*)mesh, cursors, records);

    scatter_reduce_kernel<<<NB * NS, 1024, 0, stream>>>(
        records, cursors, (const int4*)gt, thr, sums, counts);

    final_kernel<<<1, 64, 0, stream>>>(sums, counts, pv, out);
}

// Round 6
// 167.431 us; speedup vs baseline: 3.7128x; 3.7128x over previous
//
#include <hip/hip_runtime.h>

// SdfParseLoss: scatter-min/max of sdf over pixel grid, then masked mean loss.
// H=256, W=192, B=64, V=100000. Output: 64 floats.
//
// Round 6: two-pass binning with BLOCK-LOCAL compaction (round 5's global
// contended cursor atomics-with-return were a 483us serialization disaster).
//  Pass 1: block (b,c) streams its 1/8 chunk of batch b's verts once,
//          LDS cursor atomicAdd (per-block, uncontended) -> writes
//          rec32 = p_local(14b)<<18 | key18 into its PRIVATE bucket
//          records[b][c][q][CAP]; per-bucket counts to global (plain store).
//  Pass 2: block (b,q) drains its 8 private buckets -> LDS atomicMin
//          (gt==0 pixels store inverted key so min == max), then reduces.
// key18 = top 18 bits of order-preserving fkey, round-to-nearest: <=2^-10
// relative error, ~1000x under threshold (round 5 passed absmax 0.0).
// Logical bytes ~130MB vs round-3/4's S*77MB replication.

#define HH 256
#define WW 192
#define HW (HH * WW)
#define NB 64
#define NV 100000
#define NS 4                     // slices of 64 rows
#define RANGE (HW / NS)          // 12288 pixels per slice
#define NC 8                     // vertex chunks per batch
#define CHUNK (NV / NC)          // 12500 verts
#define F4B (NV / 4 / NC)        // 3125 float4 groups per pass-1 block
#define CAP 3000                 // per-(b,c,q) bucket cap (mean 2582, ~9 sigma)

// Order-preserving float <-> uint transform so unsigned min gives float min.
__device__ __forceinline__ unsigned fkey(float f) {
    unsigned u = __float_as_uint(f);
    return (u & 0x80000000u) ? ~u : (u | 0x80000000u);
}
__device__ __forceinline__ float funkey(unsigned k) {
    unsigned u = (k & 0x80000000u) ? (k ^ 0x80000000u) : ~k;
    return __uint_as_float(u);
}
// 18-bit order-preserving quantization (round to nearest grid point).
__device__ __forceinline__ unsigned key18(float f) {
    unsigned k = fkey(f);
    if (k >= 0xFFFFE000u) return 0x3FFFFu;       // avoid +0x2000 overflow
    return (k + 0x2000u) >> 14;                  // monotone round-to-nearest
}

__global__ __launch_bounds__(512) void bin_kernel(
        const float4* __restrict__ sdf4,
        const float4* __restrict__ mesh4,
        unsigned* __restrict__ cnt,              // [NB*NC*NS]
        unsigned* __restrict__ records) {        // [NB*NC*NS*CAP]
    __shared__ unsigned lcur[NS];
    const int b = blockIdx.x >> 3;               // NC == 8
    const int c = blockIdx.x & 7;
    const int tid = threadIdx.x;
    if (tid < NS) lcur[tid] = 0;
    __syncthreads();

    const float4* sbase = sdf4  + (size_t)b * (NV / 4) + (size_t)c * F4B;
    const float4* mbase = mesh4 + (size_t)b * (NV / 2) + (size_t)c * F4B * 2;
    unsigned* rbase = records + (size_t)(b * NC + c) * NS * CAP;

    for (int g = tid; g < F4B; g += 512) {
        float4 s4 = sbase[g];
        float4 ma = mbase[2 * g];
        float4 mb = mbase[2 * g + 1];
        float xs[4] = {ma.x, ma.z, mb.x, mb.z};
        float ys[4] = {ma.y, ma.w, mb.y, mb.w};
        float ss[4] = {s4.x, s4.y, s4.z, s4.w};
        #pragma unroll
        for (int j = 0; j < 4; ++j) {
            int x = (int)xs[j];   // trunc toward zero == jnp astype(int32)
            int y = (int)ys[j];
            if ((unsigned)x < WW && (unsigned)y < HH) {
                int q = y >> 6;                  // 64 rows per slice
                unsigned pos = atomicAdd(&lcur[q], 1u);   // LDS, per-block
                if (pos < CAP)
                    rbase[q * CAP + pos] =
                        ((unsigned)((y & 63) * WW + x) << 18) | key18(ss[j]);
            }
        }
    }
    __syncthreads();
    if (tid < NS) cnt[(b * NC + c) * NS + tid] = lcur[tid];
}

__global__ __launch_bounds__(1024) void scatter_reduce_kernel(
        const unsigned* __restrict__ records,
        const unsigned* __restrict__ cnt,
        const int4* __restrict__ gt4,
        const float* __restrict__ thr_p,
        float* __restrict__ sums,
        unsigned* __restrict__ counts) {
    __shared__ unsigned ldsk[RANGE];             // 48 KB
    __shared__ unsigned char gtb[RANGE];         // 12 KB
    const int b = blockIdx.x >> 2;
    const int q = blockIdx.x & 3;
    const int tid = threadIdx.x;

    int lpos = 0;
    for (int j = tid; j < RANGE; j += 1024) ldsk[j] = 0xFFFFFFFFu;
    const int4* gbase = gt4 + ((size_t)b * HW + (size_t)q * RANGE) / 4;
    for (int j = tid; j < RANGE / 4; j += 1024) {
        int4 g = gbase[j];
        gtb[4 * j + 0] = (unsigned char)g.x;
        gtb[4 * j + 1] = (unsigned char)g.y;
        gtb[4 * j + 2] = (unsigned char)g.z;
        gtb[4 * j + 3] = (unsigned char)g.w;
        lpos |= (g.x == 1) | (g.y == 1) | (g.z == 1) | (g.w == 1);
    }
    __syncthreads();

    // drain the 8 private buckets for this (b, slice)
    for (int c = 0; c < NC; ++c) {
        unsigned n = cnt[(b * NC + c) * NS + q];
        if (n > CAP) n = CAP;
        const unsigned* rb = records + ((size_t)(b * NC + c) * NS + q) * CAP;
        for (unsigned i = tid; i < n; i += 1024) {
            unsigned r = rb[i];
            unsigned p = r >> 18;
            unsigned k = r & 0x3FFFFu;
            if (gtb[p] == 0) k ^= 0x3FFFFu;      // neg pixel: min(~k) == max
            atomicMin(&ldsk[p], k);
        }
    }
    __syncthreads();

    const float thr = thr_p[0];
    float lsum = 0.f;
    for (int j = tid; j < RANGE; j += 1024) {
        unsigned k = ldsk[j];
        if (k <= 0x3FFFFu) {                     // empty pixels contribute 0
            if (gtb[j]) lsum += fabsf(funkey(k << 14));
            else        lsum += fabsf(funkey((k ^ 0x3FFFFu) << 14) - thr);
        }
    }
    #pragma unroll
    for (int off = 32; off > 0; off >>= 1)
        lsum += __shfl_down(lsum, off, 64);
    unsigned long long m = __ballot(lpos != 0);
    if ((tid & 63) == 0) {
        atomicAdd(&sums[b], lsum);
        if (m) atomicOr(&counts[b], 1u);
    }
}

__global__ void final_kernel(const float* __restrict__ sums,
                             const unsigned* __restrict__ counts,
                             const float* __restrict__ pv,
                             float* __restrict__ out) {
    int b = threadIdx.x;
    if (b < NB) {
        float s = sums[b] * (1.0f / HW) * pv[b];
        out[b] = counts[b] ? s : 0.0f;
    }
}

extern "C" void kernel_launch(void* const* d_in, const int* in_sizes, int n_in,
                              void* d_out, int out_size, void* d_ws, size_t ws_size,
                              hipStream_t stream) {
    const float* sdf  = (const float*)d_in[0];
    const float* mesh = (const float*)d_in[1];
    const int*   gt   = (const int*)d_in[2];
    const float* thr  = (const float*)d_in[3];
    const float* pv   = (const float*)d_in[5];   // parse_valid [B,1,1]
    float* out = (float*)d_out;

    // ws: [cnt 8KB][sums 256B][counts 256B][records 24.58MB]  (< 25.2MB proven)
    unsigned* cnt     = (unsigned*)d_ws;
    float*    sums    = (float*)((char*)d_ws + 8192);
    unsigned* counts  = (unsigned*)((char*)d_ws + 8448);
    unsigned* records = (unsigned*)((char*)d_ws + 8704);

    hipMemsetAsync(sums, 0, 512, stream);        // sums + counts only

    bin_kernel<<<NB * NC, 512, 0, stream>>>(
        (const float4*)sdf, (const float4*)mesh, cnt, records);

    scatter_reduce_kernel<<<NB * NS, 1024, 0, stream>>>(
        records, cnt, (const int4*)gt, thr, sums, counts);

    final_kernel<<<1, 64, 0, stream>>>(sums, counts, pv, out);
}